// Round 1
// baseline (65.458 us; speedup 1.0000x reference)
//
#include <hip/hip_runtime.h>

// BPS condition tokenizer: for each (batch b, basis p), nearest cloud point
// argmin over N, output [dist, dx, dy, dz].
// B=16, N=4096, P=4096, D=3. Output [B, P, 4] float32.

#define NB 16
#define NN 4096
#define NP 4096
#define PT 256            // basis points per block
#define NG 4              // N-split groups per block
#define THREADS (PT * NG) // 1024

__global__ __launch_bounds__(THREADS) void bps_kernel(
    const float* __restrict__ pc,     // [B, N, 3]
    const float* __restrict__ basis,  // [P, 3]
    float* __restrict__ out)          // [B, P, 4]
{
#pragma clang fp contract(off)
    // cloud[n] = (-2x, -2y, -2z, x^2+y^2+z^2)  — the -2 prescale is an exact
    // power-of-two transform, so (bsq + s) + dot(scaled, basis) is bit-identical
    // to the reference's (b_sq + pc_sq) - 2*cross.
    __shared__ float4 cloud[NN];
    __shared__ float  redMin[NG - 1][PT];
    __shared__ int    redIdx[NG - 1][PT];

    const int b     = blockIdx.x / (NP / PT);
    const int ptile = blockIdx.x % (NP / PT);
    const int t     = threadIdx.x;
    const int pl    = t & (PT - 1);
    const int g     = t >> 8;  // 0..3

    // --- stage cloud for batch b into LDS ---
    const float* pcb = pc + (size_t)b * NN * 3;
    for (int n = t; n < NN; n += THREADS) {
        float x = pcb[n * 3 + 0];
        float y = pcb[n * 3 + 1];
        float z = pcb[n * 3 + 2];
        float s = (x * x + y * y) + z * z;  // same op order as ref pc_sq
        cloud[n] = make_float4(-2.0f * x, -2.0f * y, -2.0f * z, s);
    }

    const int p = ptile * PT + pl;
    const float bx = basis[p * 3 + 0];
    const float by = basis[p * 3 + 1];
    const float bz = basis[p * 3 + 2];
    const float bsq = (bx * bx + by * by) + bz * bz;  // ref b_sq op order

    __syncthreads();

    // --- scan this group's quarter of N ---
    float mind = __builtin_inff();
    int   mini = 0;
    const int n0 = g * (NN / NG);
    const int n1 = n0 + (NN / NG);
    for (int n = n0; n < n1; ++n) {
        float4 c = cloud[n];                         // uniform addr -> broadcast
        float cr = (c.x * bx + c.y * by) + c.z * bz; // == -2*cross (exact scale)
        float d2 = (bsq + c.w) + cr;                 // == (bsq+pcsq) - 2*cross
        if (d2 < mind) { mind = d2; mini = n; }      // strict < => first index
    }

    // --- combine the 4 groups (ascending g + strict < keeps first index) ---
    if (g > 0) { redMin[g - 1][pl] = mind; redIdx[g - 1][pl] = mini; }
    __syncthreads();
    if (g == 0) {
        for (int gg = 0; gg < NG - 1; ++gg) {
            float m2 = redMin[gg][pl];
            int   i2 = redIdx[gg][pl];
            if (m2 < mind) { mind = m2; mini = i2; }
        }
        float4 c = cloud[mini];
        float nx = -0.5f * c.x;  // exact recovery of original coords
        float ny = -0.5f * c.y;
        float nz = -0.5f * c.z;
        float dx = nx - bx, dy = ny - by, dz = nz - bz;
        float dist = sqrtf((dx * dx + dy * dy) + dz * dz);  // ref op order
        ((float4*)out)[(size_t)b * NP + p] = make_float4(dist, dx, dy, dz);
    }
}

extern "C" void kernel_launch(void* const* d_in, const int* in_sizes, int n_in,
                              void* d_out, int out_size, void* d_ws, size_t ws_size,
                              hipStream_t stream) {
    const float* pc    = (const float*)d_in[0];  // [16, 4096, 3]
    const float* basis = (const float*)d_in[1];  // [4096, 3]
    float* out = (float*)d_out;                  // [16, 4096, 4]

    dim3 grid(NB * (NP / PT));  // 256 blocks
    dim3 block(THREADS);        // 1024 threads
    bps_kernel<<<grid, block, 0, stream>>>(pc, basis, out);
}